// Round 5
// baseline (1419.504 us; speedup 1.0000x reference)
//
#include <hip/hip_runtime.h>
#include <hip/hip_bf16.h>

// LSTMEncoder: B=65536, T=25, I=4, H=64, 2 layers, out = h2 at t=4,9,14,19,24.
// Reference is float32 (numpy). f32-equivalent matmul accuracy on the MFMA
// pipe via split precision: v = hi + lo (both bf16),
//   h@W ~= h_hi@W_hi + h_hi@W_lo + h_lo@W_hi   (lo@lo dropped, ~2^-18 rel)
// bf16 x bf16 products are exact in the f32 MFMA accumulator. Elementwise is
// pure f32 (hw exp2/rcp). x-GEMM folds all 3 split terms into ONE K=32 MFMA.
//
// R5: __launch_bounds__(256,2) -> 2 blocks/CU resident (VGPR 208<=256,
// LDS 77KiB*2<=160KiB). R4 ran 1 block/CU (Occupancy 11.8%): MFMA 29.6% and
// VALU 52% serialized within the single wave/SIMD. With 2 waves/SIMD the
// pipes overlap across waves (m114) and barrier stalls hide.
//
// 1 block = 64 batch rows, 4 waves. h1/h2 ping-pong in LDS as hi/lo bf16
// pairs. Each wave owns the same j-range of all 4 gates -> LSTM cell fully
// in-lane; c-state f32 in registers.
// MFMA 16x16x32 bf16 layouts (measured, learn_hip m89/m120):
//   A[m][k]: m=lane&15, k=(lane>>4)*8+e ; B[k][n]: n=lane&15, k=(lane>>4)*8+e
//   C/D    : col=lane&15, row=(lane>>4)*4+reg

typedef short short8 __attribute__((ext_vector_type(8)));
typedef float floatx4 __attribute__((ext_vector_type(4)));

namespace {
constexpr int T_ = 25;
constexpr int I_ = 4;
constexpr int MB = 64;     // batch rows per block
constexpr int HSTR = 72;   // LDS row stride (shorts): 144B -> 4-bank rotation, 16B aligned
constexpr int XSTR = 40;   // x tile stride (shorts): 80B, 16B aligned
}

__device__ __forceinline__ float sigm_(float x) {
  float t = __builtin_amdgcn_exp2f(x * -1.44269504088896340736f);  // e^-x
  return __builtin_amdgcn_rcpf(1.0f + t);                          // 1/(1+e^-x)
}
__device__ __forceinline__ float tanh_(float x) {
  float t = __builtin_amdgcn_exp2f(x * -2.88539008177792681472f);  // e^-2x
  return 2.0f * __builtin_amdgcn_rcpf(1.0f + t) - 1.0f;            // 2*sigm(2x)-1
}
__device__ __forceinline__ unsigned short f2bf_(float f) {  // RNE f32->bf16
  unsigned u = __float_as_uint(f);
  u += 0x7FFFu + ((u >> 16) & 1u);
  return (unsigned short)(u >> 16);
}
__device__ __forceinline__ float bf2f_(unsigned short s) {
  return __uint_as_float(((unsigned)s) << 16);
}
// split f32 -> (hi, lo) bf16 pair; hi + lo == f to ~2^-18 rel
__device__ __forceinline__ void splitf_(float f, unsigned short& hi, unsigned short& lo) {
  hi = f2bf_(f);
  lo = f2bf_(f - bf2f_(hi));
}
__device__ __forceinline__ void split8_(const float* __restrict__ p, short8& hi, short8& lo) {
#pragma unroll
  for (int i = 0; i < 8; ++i) {
    unsigned short h, l;
    splitf_(p[i], h, l);
    hi[i] = (short)h;
    lo[i] = (short)l;
  }
}

__global__ __launch_bounds__(256, 2)
void lstm2_kernel(const float* __restrict__ x,     // [B,25,4]
                  const float* __restrict__ Wih0,  // [256,4]
                  const float* __restrict__ Whh0,  // [256,64]
                  const float* __restrict__ b0,    // [256]
                  const float* __restrict__ Wih1,  // [256,64]
                  const float* __restrict__ Whh1,  // [256,64]
                  const float* __restrict__ b1,    // [256]
                  float* __restrict__ out) {       // [B,5,64]
  __shared__ __align__(16) unsigned short H1h[2][MB * HSTR];
  __shared__ __align__(16) unsigned short H1l[2][MB * HSTR];
  __shared__ __align__(16) unsigned short H2h[2][MB * HSTR];
  __shared__ __align__(16) unsigned short H2l[2][MB * HSTR];
  __shared__ __align__(16) unsigned short XB[MB * XSTR];

  const int tid = threadIdx.x;
  const int lane = tid & 63;
  const int w = tid >> 6;
  const int l = lane & 15;
  const int q = lane >> 4;
  const int mbase = blockIdx.x * MB;
  const int j = w * 16 + l;  // hidden index owned by this lane (all 4 gates)

  // ---- register-resident weight B-fragments (hi/lo): B[k][n], n = 64*g + j --
  short8 B1h[4][2], B1l[4][2];          // Whh0
  short8 B2h[4][4], B2l[4][4];          // [0..1]=Wih1, [2..3]=Whh1
  short8 BXf[4];                        // Wih0 folded hi/lo K=32 tile
  floatx4 bias0v[4], bias1v[4];
#pragma unroll
  for (int g = 0; g < 4; ++g) {
    const int n = g * 64 + j;
    split8_(Whh0 + n * 64 + q * 8,      B1h[g][0], B1l[g][0]);
    split8_(Whh0 + n * 64 + 32 + q * 8, B1h[g][1], B1l[g][1]);
    split8_(Wih1 + n * 64 + q * 8,      B2h[g][0], B2l[g][0]);
    split8_(Wih1 + n * 64 + 32 + q * 8, B2h[g][1], B2l[g][1]);
    split8_(Whh1 + n * 64 + q * 8,      B2h[g][2], B2l[g][2]);
    split8_(Whh1 + n * 64 + 32 + q * 8, B2h[g][3], B2l[g][3]);
    short8 bx = {0, 0, 0, 0, 0, 0, 0, 0};
    if (q < 2) {
#pragma unroll
      for (int i = 0; i < 4; ++i) {
        unsigned short wh, wl;
        splitf_(Wih0[n * 4 + i], wh, wl);
        bx[i] = (short)wh;                    // rows 0..3 / 8..11: W_hi
        if (q == 0) bx[4 + i] = (short)wl;    // rows 4..7: W_lo
      }
    }
    BXf[g] = bx;
    float bb0 = b0[n], bb1 = b1[n];
    bias0v[g] = (floatx4){bb0, bb0, bb0, bb0};
    bias1v[g] = (floatx4){bb1, bb1, bb1, bb1};
  }

  for (int idx = tid; idx < MB * 64; idx += 256) {
    int m = idx >> 6, k = idx & 63;
    H1h[0][m * HSTR + k] = 0;
    H1l[0][m * HSTR + k] = 0;
    H2h[0][m * HSTR + k] = 0;
    H2l[0][m * HSTR + k] = 0;
  }
  for (int idx = tid; idx < MB * XSTR; idx += 256) XB[idx] = 0;
  {
    int m = tid >> 2, ii = tid & 3;
    float xv = x[(mbase + m) * (T_ * I_) + ii];
    unsigned short xh, xl;
    splitf_(xv, xh, xl);
    XB[m * XSTR + ii] = xh;
    XB[m * XSTR + 4 + ii] = xh;
    XB[m * XSTR + 8 + ii] = xl;
  }

  float c1[16], c2[16];  // f32 cell state
#pragma unroll
  for (int k = 0; k < 16; ++k) { c1[k] = 0.f; c2[k] = 0.f; }

  __syncthreads();

#pragma unroll 1
  for (int t = 0; t < T_; ++t) {
    const int p = t & 1;

    // ---------- layer 1: z = x@Wih0^T + h1@Whh0^T + b0 (f32-accurate) -------
#pragma unroll
    for (int mt = 0; mt < 4; ++mt) {
      const int row = mt * 16 + l;
      short8 a0h = *(const short8*)&H1h[p][row * HSTR + q * 8];
      short8 a1h = *(const short8*)&H1h[p][row * HSTR + 32 + q * 8];
      short8 a0l = *(const short8*)&H1l[p][row * HSTR + q * 8];
      short8 a1l = *(const short8*)&H1l[p][row * HSTR + 32 + q * 8];
      short8 ax  = *(const short8*)&XB[row * XSTR + q * 8];
      floatx4 zs[4];
#pragma unroll
      for (int g = 0; g < 4; ++g) {
        floatx4 a_ = bias0v[g];
        a_ = __builtin_amdgcn_mfma_f32_16x16x32_bf16(ax,  BXf[g],    a_, 0, 0, 0);
        a_ = __builtin_amdgcn_mfma_f32_16x16x32_bf16(a0h, B1h[g][0], a_, 0, 0, 0);
        a_ = __builtin_amdgcn_mfma_f32_16x16x32_bf16(a1h, B1h[g][1], a_, 0, 0, 0);
        a_ = __builtin_amdgcn_mfma_f32_16x16x32_bf16(a0h, B1l[g][0], a_, 0, 0, 0);
        a_ = __builtin_amdgcn_mfma_f32_16x16x32_bf16(a1h, B1l[g][1], a_, 0, 0, 0);
        a_ = __builtin_amdgcn_mfma_f32_16x16x32_bf16(a0l, B1h[g][0], a_, 0, 0, 0);
        a_ = __builtin_amdgcn_mfma_f32_16x16x32_bf16(a1l, B1h[g][1], a_, 0, 0, 0);
        zs[g] = a_;
      }
#pragma unroll
      for (int r = 0; r < 4; ++r) {
        float si = sigm_(zs[0][r]);
        float sf = sigm_(zs[1][r]);
        float tg = tanh_(zs[2][r]);
        float so = sigm_(zs[3][r]);
        float cc = sf * c1[mt * 4 + r] + si * tg;
        c1[mt * 4 + r] = cc;
        float h = so * tanh_(cc);
        unsigned short hh, hl;
        splitf_(h, hh, hl);
        const int m = mt * 16 + q * 4 + r;
        H1h[p ^ 1][m * HSTR + j] = hh;
        H1l[p ^ 1][m * HSTR + j] = hl;
      }
    }
    __syncthreads();

    if (t + 1 < T_) {  // stage x(t+1); consumed after next barrier
      int m = tid >> 2, ii = tid & 3;
      float xv = x[(mbase + m) * (T_ * I_) + (t + 1) * I_ + ii];
      unsigned short xh, xl;
      splitf_(xv, xh, xl);
      XB[m * XSTR + ii] = xh;
      XB[m * XSTR + 4 + ii] = xh;
      XB[m * XSTR + 8 + ii] = xl;
    }

    // ---------- layer 2: z = h1new@Wih1^T + h2@Whh1^T + b1 ------------------
    const bool do_out = (t % 5 == 4);
    const int kk = t / 5;
#pragma unroll
    for (int mt = 0; mt < 4; ++mt) {
      const int row = mt * 16 + l;
      short8 n0h = *(const short8*)&H1h[p ^ 1][row * HSTR + q * 8];
      short8 n1h = *(const short8*)&H1h[p ^ 1][row * HSTR + 32 + q * 8];
      short8 n0l = *(const short8*)&H1l[p ^ 1][row * HSTR + q * 8];
      short8 n1l = *(const short8*)&H1l[p ^ 1][row * HSTR + 32 + q * 8];
      short8 m0h = *(const short8*)&H2h[p][row * HSTR + q * 8];
      short8 m1h = *(const short8*)&H2h[p][row * HSTR + 32 + q * 8];
      short8 m0l = *(const short8*)&H2l[p][row * HSTR + q * 8];
      short8 m1l = *(const short8*)&H2l[p][row * HSTR + 32 + q * 8];
      floatx4 zs[4];
#pragma unroll
      for (int g = 0; g < 4; ++g) {
        floatx4 a_ = bias1v[g];
        a_ = __builtin_amdgcn_mfma_f32_16x16x32_bf16(n0h, B2h[g][0], a_, 0, 0, 0);
        a_ = __builtin_amdgcn_mfma_f32_16x16x32_bf16(n1h, B2h[g][1], a_, 0, 0, 0);
        a_ = __builtin_amdgcn_mfma_f32_16x16x32_bf16(n0h, B2l[g][0], a_, 0, 0, 0);
        a_ = __builtin_amdgcn_mfma_f32_16x16x32_bf16(n1h, B2l[g][1], a_, 0, 0, 0);
        a_ = __builtin_amdgcn_mfma_f32_16x16x32_bf16(n0l, B2h[g][0], a_, 0, 0, 0);
        a_ = __builtin_amdgcn_mfma_f32_16x16x32_bf16(n1l, B2h[g][1], a_, 0, 0, 0);
        a_ = __builtin_amdgcn_mfma_f32_16x16x32_bf16(m0h, B2h[g][2], a_, 0, 0, 0);
        a_ = __builtin_amdgcn_mfma_f32_16x16x32_bf16(m1h, B2h[g][3], a_, 0, 0, 0);
        a_ = __builtin_amdgcn_mfma_f32_16x16x32_bf16(m0h, B2l[g][2], a_, 0, 0, 0);
        a_ = __builtin_amdgcn_mfma_f32_16x16x32_bf16(m1h, B2l[g][3], a_, 0, 0, 0);
        a_ = __builtin_amdgcn_mfma_f32_16x16x32_bf16(m0l, B2h[g][2], a_, 0, 0, 0);
        a_ = __builtin_amdgcn_mfma_f32_16x16x32_bf16(m1l, B2h[g][3], a_, 0, 0, 0);
        zs[g] = a_;
      }
#pragma unroll
      for (int r = 0; r < 4; ++r) {
        float si = sigm_(zs[0][r]);
        float sf = sigm_(zs[1][r]);
        float tg = tanh_(zs[2][r]);
        float so = sigm_(zs[3][r]);
        float cc = sf * c2[mt * 4 + r] + si * tg;
        c2[mt * 4 + r] = cc;
        float h = so * tanh_(cc);
        unsigned short hh, hl;
        splitf_(h, hh, hl);
        const int m = mt * 16 + q * 4 + r;
        H2h[p ^ 1][m * HSTR + j] = hh;
        H2l[p ^ 1][m * HSTR + j] = hl;
        if (do_out) out[(size_t)(mbase + m) * 320 + (size_t)kk * 64 + j] = h;
      }
    }
    __syncthreads();
  }
}

extern "C" void kernel_launch(void* const* d_in, const int* in_sizes, int n_in,
                              void* d_out, int out_size, void* d_ws, size_t ws_size,
                              hipStream_t stream) {
  const float* xp   = (const float*)d_in[0];
  const float* Wih0 = (const float*)d_in[1];
  const float* Whh0 = (const float*)d_in[2];
  const float* b0   = (const float*)d_in[3];
  const float* Wih1 = (const float*)d_in[4];
  const float* Whh1 = (const float*)d_in[5];
  const float* b1   = (const float*)d_in[6];
  float* outp = (float*)d_out;

  const int B = in_sizes[0] / (T_ * I_);  // 65536
  dim3 grid(B / MB), block(256);
  hipLaunchKernelGGL(lstm2_kernel, grid, block, 0, stream,
                     xp, Wih0, Whh0, b0, Wih1, Whh1, b1, outp);
}

// Round 7
// 600.942 us; speedup vs baseline: 2.3621x; 2.3621x over previous
//
#include <hip/hip_runtime.h>
#include <hip/hip_bf16.h>

// LSTMEncoder: B=65536, T=25, I=4, H=64, 2 layers, out = h2 at t=4,9,14,19,24.
// Reference compare target is bf16(f32 ref); only an f32-accurate trajectory
// passes (R2/R6: any 16-bit matmul saturates at ~1.15e-2 via recurrent
// amplification). So: R4's split-precision matmul, v = hi + lo (bf16 pairs),
//   h@W ~= h_hi@W_hi + h_hi@W_lo + h_lo@W_hi  (exact products in f32 MFMA acc)
// Elementwise pure f32 (hw exp2/rcp).
//
// R7: WAVE SPECIALIZATION. 512-thread block: waves 0-3 own layer 1, waves 4-7
// own layer 2, software-pipelined (L2 does h2(t-1) while L1 does h1(t); one
// barrier/iter, 26 iters). Each wave holds only its layer's weights
// (~160/~220 VGPR incl. MFMA acc, unified file) -> 2 waves/SIMD resident
// (one L1 + one L2 per SIMD) -> MFMA/VALU overlap across waves (m114).
// R4 ran 1 wave/SIMD, phase-lockstep, ~70% latency-exposed (746 us).
// R5 showed (256,2) without the split spills (VGPR 128, FETCH 2.5 GB).
//
// MFMA 16x16x32 bf16 layouts (measured, learn_hip m89/m120):
//   A[m][k]: m=lane&15, k=(lane>>4)*8+e ; B[k][n]: n=lane&15, k=(lane>>4)*8+e
//   C/D    : col=lane&15, row=(lane>>4)*4+reg

typedef short short8 __attribute__((ext_vector_type(8)));
typedef float floatx4 __attribute__((ext_vector_type(4)));

namespace {
constexpr int T_ = 25;
constexpr int I_ = 4;
constexpr int MB = 64;     // batch rows per block
constexpr int HSTR = 72;   // LDS row stride (shorts): 144B, 16B-aligned reads
constexpr int XSTR = 40;   // x tile stride (shorts)
}

__device__ __forceinline__ float sigm_(float x) {
  float t = __builtin_amdgcn_exp2f(x * -1.44269504088896340736f);  // e^-x
  return __builtin_amdgcn_rcpf(1.0f + t);
}
__device__ __forceinline__ float tanh_(float x) {
  float t = __builtin_amdgcn_exp2f(x * -2.88539008177792681472f);  // e^-2x
  return 2.0f * __builtin_amdgcn_rcpf(1.0f + t) - 1.0f;
}
__device__ __forceinline__ unsigned short f2bf_(float f) {  // RNE f32->bf16
  unsigned u = __float_as_uint(f);
  u += 0x7FFFu + ((u >> 16) & 1u);
  return (unsigned short)(u >> 16);
}
__device__ __forceinline__ float bf2f_(unsigned short s) {
  return __uint_as_float(((unsigned)s) << 16);
}
__device__ __forceinline__ void splitf_(float f, unsigned short& hi, unsigned short& lo) {
  hi = f2bf_(f);
  lo = f2bf_(f - bf2f_(hi));
}
__device__ __forceinline__ void split8_(const float* __restrict__ p, short8& hi, short8& lo) {
#pragma unroll
  for (int i = 0; i < 8; ++i) {
    unsigned short h, l;
    splitf_(p[i], h, l);
    hi[i] = (short)h;
    lo[i] = (short)l;
  }
}

__global__ __launch_bounds__(512, 2)
void lstm2_kernel(const float* __restrict__ x,     // [B,25,4]
                  const float* __restrict__ Wih0,  // [256,4]
                  const float* __restrict__ Whh0,  // [256,64]
                  const float* __restrict__ b0,    // [256]
                  const float* __restrict__ Wih1,  // [256,64]
                  const float* __restrict__ Whh1,  // [256,64]
                  const float* __restrict__ b1,    // [256]
                  float* __restrict__ out) {       // [B,5,64]
  // h1(t) lives in H1*[t&1]; h2(t) in H2*[t&1]; x(t) in XB[t&1].
  __shared__ __align__(16) unsigned short H1h[2][MB * HSTR];
  __shared__ __align__(16) unsigned short H1l[2][MB * HSTR];
  __shared__ __align__(16) unsigned short H2h[2][MB * HSTR];
  __shared__ __align__(16) unsigned short H2l[2][MB * HSTR];
  __shared__ __align__(16) unsigned short XB[2][MB * XSTR];

  const int tid = threadIdx.x;
  const int lane = tid & 63;
  const int w = tid >> 6;   // 0..7
  const int l = lane & 15;
  const int q = lane >> 4;
  const int mbase = blockIdx.x * MB;

  // ---- init LDS: zero the [1] state buffers (h(-1)=0) + both XB buffers ----
  for (int idx = tid; idx < MB * 64; idx += 512) {
    int m = idx >> 6, k = idx & 63;
    H1h[1][m * HSTR + k] = 0;
    H1l[1][m * HSTR + k] = 0;
    H2h[1][m * HSTR + k] = 0;
    H2l[1][m * HSTR + k] = 0;
  }
  for (int idx = tid; idx < 2 * MB * XSTR; idx += 512) (&XB[0][0])[idx] = 0;
  if (tid < 256) {  // stage x(0) into XB[0]
    int m = tid >> 2, ii = tid & 3;
    unsigned short xh, xl;
    splitf_(x[(mbase + m) * (T_ * I_) + ii], xh, xl);
    XB[0][m * XSTR + ii] = xh;
    XB[0][m * XSTR + 4 + ii] = xh;
    XB[0][m * XSTR + 8 + ii] = xl;
  }
  __syncthreads();

  if (w < 4) {
    // ==================== LAYER-1 WAVES (0..3) ====================
    const int j = w * 16 + l;  // hidden col owned (all 4 gates)
    short8 B1h[4][2], B1l[4][2], BXf[4];
    floatx4 bias0v[4];
#pragma unroll
    for (int g = 0; g < 4; ++g) {
      const int n = g * 64 + j;
      split8_(Whh0 + n * 64 + q * 8,      B1h[g][0], B1l[g][0]);
      split8_(Whh0 + n * 64 + 32 + q * 8, B1h[g][1], B1l[g][1]);
      short8 bx = {0, 0, 0, 0, 0, 0, 0, 0};
      if (q < 2) {
#pragma unroll
        for (int i = 0; i < 4; ++i) {
          unsigned short wh, wl;
          splitf_(Wih0[n * 4 + i], wh, wl);
          bx[i] = (short)wh;                  // rows 0..3 / 8..11: W_hi
          if (q == 0) bx[4 + i] = (short)wl;  // rows 4..7: W_lo
        }
      }
      BXf[g] = bx;
      float bb = b0[n];
      bias0v[g] = (floatx4){bb, bb, bb, bb};
    }
    float c1[16];
#pragma unroll
    for (int k = 0; k < 16; ++k) c1[k] = 0.f;

#pragma unroll 1
    for (int tt = 0; tt < T_ + 1; ++tt) {
      if (tt < T_) {
        const int p = tt & 1;  // write h1(tt) -> H1*[p]; read h1(tt-1) <- H1*[p^1]
#pragma unroll
        for (int mt = 0; mt < 4; ++mt) {
          const int row = mt * 16 + l;
          short8 a0h = *(const short8*)&H1h[p ^ 1][row * HSTR + q * 8];
          short8 a1h = *(const short8*)&H1h[p ^ 1][row * HSTR + 32 + q * 8];
          short8 a0l = *(const short8*)&H1l[p ^ 1][row * HSTR + q * 8];
          short8 a1l = *(const short8*)&H1l[p ^ 1][row * HSTR + 32 + q * 8];
          short8 ax  = *(const short8*)&XB[p][row * XSTR + q * 8];
          floatx4 zs[4];
#pragma unroll
          for (int g = 0; g < 4; ++g) {
            floatx4 a_ = bias0v[g];
            a_ = __builtin_amdgcn_mfma_f32_16x16x32_bf16(ax,  BXf[g],    a_, 0, 0, 0);
            a_ = __builtin_amdgcn_mfma_f32_16x16x32_bf16(a0h, B1h[g][0], a_, 0, 0, 0);
            a_ = __builtin_amdgcn_mfma_f32_16x16x32_bf16(a1h, B1h[g][1], a_, 0, 0, 0);
            a_ = __builtin_amdgcn_mfma_f32_16x16x32_bf16(a0h, B1l[g][0], a_, 0, 0, 0);
            a_ = __builtin_amdgcn_mfma_f32_16x16x32_bf16(a1h, B1l[g][1], a_, 0, 0, 0);
            a_ = __builtin_amdgcn_mfma_f32_16x16x32_bf16(a0l, B1h[g][0], a_, 0, 0, 0);
            a_ = __builtin_amdgcn_mfma_f32_16x16x32_bf16(a1l, B1h[g][1], a_, 0, 0, 0);
            zs[g] = a_;
          }
#pragma unroll
          for (int r = 0; r < 4; ++r) {
            float si = sigm_(zs[0][r]);
            float sf = sigm_(zs[1][r]);
            float tg = tanh_(zs[2][r]);
            float so = sigm_(zs[3][r]);
            float cc = sf * c1[mt * 4 + r] + si * tg;
            c1[mt * 4 + r] = cc;
            float h = so * tanh_(cc);
            unsigned short hh, hl;
            splitf_(h, hh, hl);
            const int m = mt * 16 + q * 4 + r;
            H1h[p][m * HSTR + j] = hh;
            H1l[p][m * HSTR + j] = hl;
          }
        }
        if (tt + 1 < T_) {  // stage x(tt+1) into the other XB buffer
          int m = (tid & 255) >> 2, ii = tid & 3;
          unsigned short xh, xl;
          splitf_(x[(mbase + m) * (T_ * I_) + (tt + 1) * I_ + ii], xh, xl);
          XB[(tt + 1) & 1][m * XSTR + ii] = xh;
          XB[(tt + 1) & 1][m * XSTR + 4 + ii] = xh;
          XB[(tt + 1) & 1][m * XSTR + 8 + ii] = xl;
        }
      }
      __syncthreads();  // barrier 1-per-iter, matched with L2 branch
    }
  } else {
    // ==================== LAYER-2 WAVES (4..7) ====================
    const int j = (w - 4) * 16 + l;
    short8 B2h[4][4], B2l[4][4];  // [0..1]=Wih1, [2..3]=Whh1
    floatx4 bias1v[4];
#pragma unroll
    for (int g = 0; g < 4; ++g) {
      const int n = g * 64 + j;
      split8_(Wih1 + n * 64 + q * 8,      B2h[g][0], B2l[g][0]);
      split8_(Wih1 + n * 64 + 32 + q * 8, B2h[g][1], B2l[g][1]);
      split8_(Whh1 + n * 64 + q * 8,      B2h[g][2], B2l[g][2]);
      split8_(Whh1 + n * 64 + 32 + q * 8, B2h[g][3], B2l[g][3]);
      float bb = b1[n];
      bias1v[g] = (floatx4){bb, bb, bb, bb};
    }
    float c2[16];
#pragma unroll
    for (int k = 0; k < 16; ++k) c2[k] = 0.f;

#pragma unroll 1
    for (int tt = 0; tt < T_ + 1; ++tt) {
      if (tt >= 1) {
        const int t2 = tt - 1;   // computing h2(t2)
        const int p2 = t2 & 1;   // read h1(t2) <- H1*[p2], h2(t2-1) <- H2*[p2^1]
        const bool do_out = (t2 % 5 == 4);
        const int kk = t2 / 5;
#pragma unroll
        for (int mt = 0; mt < 4; ++mt) {
          const int row = mt * 16 + l;
          short8 n0h = *(const short8*)&H1h[p2][row * HSTR + q * 8];
          short8 n1h = *(const short8*)&H1h[p2][row * HSTR + 32 + q * 8];
          short8 n0l = *(const short8*)&H1l[p2][row * HSTR + q * 8];
          short8 n1l = *(const short8*)&H1l[p2][row * HSTR + 32 + q * 8];
          short8 m0h = *(const short8*)&H2h[p2 ^ 1][row * HSTR + q * 8];
          short8 m1h = *(const short8*)&H2h[p2 ^ 1][row * HSTR + 32 + q * 8];
          short8 m0l = *(const short8*)&H2l[p2 ^ 1][row * HSTR + q * 8];
          short8 m1l = *(const short8*)&H2l[p2 ^ 1][row * HSTR + 32 + q * 8];
          floatx4 zs[4];
#pragma unroll
          for (int g = 0; g < 4; ++g) {
            floatx4 a_ = bias1v[g];
            a_ = __builtin_amdgcn_mfma_f32_16x16x32_bf16(n0h, B2h[g][0], a_, 0, 0, 0);
            a_ = __builtin_amdgcn_mfma_f32_16x16x32_bf16(n1h, B2h[g][1], a_, 0, 0, 0);
            a_ = __builtin_amdgcn_mfma_f32_16x16x32_bf16(n0h, B2l[g][0], a_, 0, 0, 0);
            a_ = __builtin_amdgcn_mfma_f32_16x16x32_bf16(n1h, B2l[g][1], a_, 0, 0, 0);
            a_ = __builtin_amdgcn_mfma_f32_16x16x32_bf16(n0l, B2h[g][0], a_, 0, 0, 0);
            a_ = __builtin_amdgcn_mfma_f32_16x16x32_bf16(n1l, B2h[g][1], a_, 0, 0, 0);
            a_ = __builtin_amdgcn_mfma_f32_16x16x32_bf16(m0h, B2h[g][2], a_, 0, 0, 0);
            a_ = __builtin_amdgcn_mfma_f32_16x16x32_bf16(m1h, B2h[g][3], a_, 0, 0, 0);
            a_ = __builtin_amdgcn_mfma_f32_16x16x32_bf16(m0h, B2l[g][2], a_, 0, 0, 0);
            a_ = __builtin_amdgcn_mfma_f32_16x16x32_bf16(m1h, B2l[g][3], a_, 0, 0, 0);
            a_ = __builtin_amdgcn_mfma_f32_16x16x32_bf16(m0l, B2h[g][2], a_, 0, 0, 0);
            a_ = __builtin_amdgcn_mfma_f32_16x16x32_bf16(m1l, B2h[g][3], a_, 0, 0, 0);
            zs[g] = a_;
          }
#pragma unroll
          for (int r = 0; r < 4; ++r) {
            float si = sigm_(zs[0][r]);
            float sf = sigm_(zs[1][r]);
            float tg = tanh_(zs[2][r]);
            float so = sigm_(zs[3][r]);
            float cc = sf * c2[mt * 4 + r] + si * tg;
            c2[mt * 4 + r] = cc;
            float h = so * tanh_(cc);
            unsigned short hh, hl;
            splitf_(h, hh, hl);
            const int m = mt * 16 + q * 4 + r;
            H2h[p2][m * HSTR + j] = hh;
            H2l[p2][m * HSTR + j] = hl;
            if (do_out) out[(size_t)(mbase + m) * 320 + (size_t)kk * 64 + j] = h;
          }
        }
      }
      __syncthreads();  // matched with L1 branch
    }
  }
}

extern "C" void kernel_launch(void* const* d_in, const int* in_sizes, int n_in,
                              void* d_out, int out_size, void* d_ws, size_t ws_size,
                              hipStream_t stream) {
  const float* xp   = (const float*)d_in[0];
  const float* Wih0 = (const float*)d_in[1];
  const float* Whh0 = (const float*)d_in[2];
  const float* b0   = (const float*)d_in[3];
  const float* Wih1 = (const float*)d_in[4];
  const float* Whh1 = (const float*)d_in[5];
  const float* b1   = (const float*)d_in[6];
  float* outp = (float*)d_out;

  const int B = in_sizes[0] / (T_ * I_);  // 65536
  dim3 grid(B / MB), block(512);
  hipLaunchKernelGGL(lstm2_kernel, grid, block, 0, stream,
                     xp, Wih0, Whh0, b0, Wih1, Whh1, b1, outp);
}